// Round 12
// baseline (136.972 us; speedup 1.0000x reference)
//
#include <hip/hip_runtime.h>
#include <stdint.h>

// Problem constants
#define BATCH 4096
#define DIN   512
#define NT    64      // trees
#define NL    64      // leaves
#define LD    128     // leaf dims

typedef __attribute__((ext_vector_type(8))) short bf16x8;
typedef __attribute__((ext_vector_type(8))) _Float16 f16x8;
typedef __attribute__((ext_vector_type(4))) float f32x4;

typedef const __attribute__((address_space(1))) unsigned char* gcp_t;
typedef __attribute__((address_space(3))) unsigned char* lp_t;

__device__ __forceinline__ void gl_lds16(const void* g, void* l) {
  __builtin_amdgcn_global_load_lds((gcp_t)g, (lp_t)l, 16, 0, 0);
}

// packed 2xf32 -> 2xbf16 (round-half-up) in 3 VALU: 2 adds + 1 v_perm
__device__ __forceinline__ unsigned pk_bf16(float a, float b) {
  union { float f; unsigned u; } ua, ub;
  ua.f = a; ub.f = b;
  return __builtin_amdgcn_perm(ub.u + 0x8000u, ua.u + 0x8000u, 0x07060302u);
}

// ---------------- merged prep kernel ----------------
// blocks [0,2048): x fp32 -> bf16
// blocks [2048,2304): W(63,512,64) -> Wt[t][n][d] bf16 (n padded to 64); 4 d-chunks per n
// blocks [2304,2432): w = lw * softmax(gates, t) -> Wv2[d][kappa] bf16, kappa = t*64+l
// blocks [2432,2464): zero d_out (folds the hipMemsetAsync launch into this kernel)
__global__ __launch_bounds__(256) void prep_all_k(
    const float* __restrict__ x, const float* __restrict__ W,
    const float* __restrict__ gates, const float* __restrict__ lw,
    unsigned short* __restrict__ xb, unsigned short* __restrict__ Wt,
    unsigned short* __restrict__ Wv2, float* __restrict__ out) {
  __shared__ float smem[12288];   // 48 KB
  const int bx = blockIdx.x;
  const int tid = threadIdx.x;

  if (bx < 2048) {
    // ---- prep x ----
    int i = bx * 256 + tid;
    float4 v = ((const float4*)x)[i];
    uint2 o;
    o.x = pk_bf16(v.x, v.y);
    o.y = pk_bf16(v.z, v.w);
    ((uint2*)xb)[i] = o;
  } else if (bx < 2304) {
    // ---- prep Wt ----
    int bb = bx - 2048;
    int n = bb >> 2, d0 = (bb & 3) * 128;
    float* buf = smem;   // [d_local][t], 128*64 floats = 32 KB
    if (n < 63) {
      for (int it = 0; it < 32; ++it) {
        int idx = it * 256 + tid;   // idx = d_local*64 + t
        buf[idx] = W[n * 32768 + (d0 + (idx >> 6)) * 64 + (idx & 63)];
      }
    }
    __syncthreads();
    int t = tid >> 2, q = tid & 3;
    unsigned vals[16];
    #pragma unroll
    for (int j = 0; j < 16; ++j) {
      float va = (n < 63) ? buf[(q * 32 + 2 * j) * 64 + t] : 0.0f;
      float vb = (n < 63) ? buf[(q * 32 + 2 * j + 1) * 64 + t] : 0.0f;
      vals[j] = (n < 63) ? pk_bf16(va, vb) : 0u;
    }
    uint4* dst = (uint4*)(Wt + t * 32768 + n * 512 + d0 + q * 32);
    const uint4* src = (const uint4*)vals;
    dst[0] = src[0]; dst[1] = src[1]; dst[2] = src[2]; dst[3] = src[3];
  } else if (bx < 2432) {
    // ---- prep Wv2 ----
    int d = bx - 2304;           // 0..127
    float* gb = smem;            // [l*64 + t]
    float* lb = smem + 4096;
    float* wv = smem + 8192;
    for (int it = 0; it < 16; ++it) {
      int idx = it * 256 + tid;  // l*64 + t
      int l = idx >> 6;
      int ga = l * 8192 + d * 64 + (idx & 63);
      gb[idx] = gates[ga];
      lb[idx] = lw[ga];
    }
    __syncthreads();
    int wave = tid >> 6, lane = tid & 63;
    for (int l = wave; l < 64; l += 4) {
      float v = gb[l * 64 + lane];
      float mx = v;
      for (int m = 32; m >= 1; m >>= 1) mx = fmaxf(mx, __shfl_xor(mx, m));
      float e = __expf(v - mx);
      float s = e;
      for (int m = 32; m >= 1; m >>= 1) s += __shfl_xor(s, m);
      wv[l * 64 + lane] = lb[l * 64 + lane] * e / s;
    }
    __syncthreads();
    #pragma unroll
    for (int c = 0; c < 2; ++c) {
      int k0 = tid * 16 + c * 8;
      unsigned o[4];
      #pragma unroll
      for (int j = 0; j < 4; ++j) {
        int ka = k0 + 2 * j, kb = k0 + 2 * j + 1;   // kappa = t*64 + l
        o[j] = pk_bf16(wv[(ka & 63) * 64 + (ka >> 6)], wv[(kb & 63) * 64 + (kb >> 6)]);
      }
      *(uint4*)(Wv2 + (long)d * 4096 + k0) = *(const uint4*)o;
    }
  } else {
    // ---- zero d_out: 2 MB = 131072 float4, 32 blocks x 256 threads x 16 ----
    float4 z = {0.f, 0.f, 0.f, 0.f};
    int base = (bx - 2432) * 256 + tid;
    float4* o4 = (float4*)out;
    #pragma unroll
    for (int k = 0; k < 16; ++k)
      o4[k * 8192 + base] = z;
  }
}

// ---------------- GEMM1 fused: logits -> sigmoid -> tree product -> P ----------------
// block: 128 batch rows x 2 trees (128 node-cols). grid (32, 32) = 1024 blocks, all
// co-resident (4/CU). XCD-aware block remap: with default lin%8->XCD round-robin,
// XCD r's 128 resident blocks cover 8 b0 x 16 t0 -> per-XCD L2 working set
// A 1 MB + B 2 MB = 3 MB < 4 MB (default mapping: 4.5 MB -> B thrashed to LLC).
// Bijective remap; correctness independent of actual XCD assignment.
// Double-buffered staging, raw s_barrier + fine vmcnt, XOR bank swizzle on staging.
// LDS = 32 KB (gbuf 128x128 f16 overlays staging; bias in VGPRs; octet XOR swizzle
// on gbuf -> SQ_LDS_BANK_CONFLICT = 0, measured R10).
// __launch_bounds__(256,4): (256,5) forces <=64 VGPR (m69 tiers) -> spill (R10).
__global__ __launch_bounds__(256, 4) void gemm1_tree_k(
    const unsigned short* __restrict__ xb,   // [4096][512] bf16
    const unsigned short* __restrict__ Wt,   // [64][64][512] bf16
    const float* __restrict__ bias,          // [63][64]
    unsigned short* __restrict__ P)          // [4096][4096] bf16, col = t*64+l
{
  __shared__ __align__(16) char smem[32768];           // union{ As[2][4K]+Bs[2][4K] , gbuf }
  unsigned short* AsB = (unsigned short*)smem;         // [2][128*32]
  unsigned short* BsB = (unsigned short*)(smem + 16384);
  _Float16* gbuf = (_Float16*)smem;                    // [128][128], octet-swizzled

  const int tid = threadIdx.x;
  const int wave = tid >> 6, lane = tid & 63;

  // XCD-aware remap (lin & 7 ~ XCD id under round-robin dispatch)
  const int lin = blockIdx.x + (blockIdx.y << 5);
  const int rr = lin & 7, kk_ = lin >> 3;
  const int b0 = (((kk_ & 7) | ((rr & 3) << 3))) * 128;
  const int t0 = (((kk_ >> 3) | ((rr >> 2) << 4))) * 2;

  const int wm = (wave >> 1) * 64, wn = (wave & 1) * 64;
  const int mrow = lane & 15, kg = lane >> 4;
  const int slot = (kg ^ ((mrow >> 1) & 3)) * 8;   // staging reader slot

  // bias in registers: lane needs bias[(j*16+mrow)*64 + t0 + tree] for j=0..3
  float bv[4];
  #pragma unroll
  for (int j = 0; j < 4; ++j) {
    int n = j * 16 + mrow;
    bv[j] = (n < 63) ? bias[n * 64 + t0 + (wave & 1)] : 0.0f;
  }

  const f32x4 zero = {0.f, 0.f, 0.f, 0.f};
  f32x4 acc[4][4];
  #pragma unroll
  for (int i = 0; i < 4; ++i)
    #pragma unroll
    for (int j = 0; j < 4; ++j) acc[i][j] = zero;

  const int g0 = wave * 64 + lane;   // granule ids (row = g>>2)
  const int g1 = g0 + 256;
  // staging chunk XOR-swizzle: lane fetches global chunk (g&3)^((g>>3)&3)
  const int c0 = ((g0 & 3) ^ ((g0 >> 3) & 3)) * 8;
  const int c1 = ((g1 & 3) ^ ((g1 >> 3) & 3)) * 8;
  const unsigned short* Ag0 = xb + (long)(b0 + (g0 >> 2)) * 512 + c0;
  const unsigned short* Ag1 = xb + (long)(b0 + (g1 >> 2)) * 512 + c1;
  const unsigned short* Bg0 = Wt + (long)(t0 * 64 + (g0 >> 2)) * 512 + c0;
  const unsigned short* Bg1 = Wt + (long)(t0 * 64 + (g1 >> 2)) * 512 + c1;
  const int lofs0 = wave * 512;          // wave-uniform LDS short-offsets
  const int lofs1 = wave * 512 + 2048;

  // preload tile 0 into buffer 0
  gl_lds16(Ag0, AsB + lofs0);
  gl_lds16(Ag1, AsB + lofs1);
  gl_lds16(Bg0, BsB + lofs0);
  gl_lds16(Bg1, BsB + lofs1);

  for (int it = 0; it < 16; ++it) {
    const int buf = (it & 1) * 4096;
    if (it < 15) {
      const int kk = (it + 1) * 32;
      const int nbuf = ((it + 1) & 1) * 4096;
      gl_lds16(Ag0 + kk, AsB + nbuf + lofs0);
      gl_lds16(Ag1 + kk, AsB + nbuf + lofs1);
      gl_lds16(Bg0 + kk, BsB + nbuf + lofs0);
      gl_lds16(Bg1 + kk, BsB + nbuf + lofs1);
      asm volatile("s_waitcnt vmcnt(4)" ::: "memory");   // tile it's 4 loads done
    } else {
      asm volatile("s_waitcnt vmcnt(0)" ::: "memory");
    }
    asm volatile("s_barrier" ::: "memory");              // all waves staged tile it

    bf16x8 fa[4], fb[4];
    #pragma unroll
    for (int i = 0; i < 4; ++i)
      fa[i] = *(const bf16x8*)(AsB + buf + (wm + i * 16 + mrow) * 32 + slot);
    #pragma unroll
    for (int j = 0; j < 4; ++j)
      fb[j] = *(const bf16x8*)(BsB + buf + (wn + j * 16 + mrow) * 32 + slot);
    #pragma unroll
    for (int i = 0; i < 4; ++i)
      #pragma unroll
      for (int j = 0; j < 4; ++j)
        acc[i][j] = __builtin_amdgcn_mfma_f32_16x16x32_bf16(fa[i], fb[j], acc[i][j], 0, 0, 0);

    asm volatile("s_waitcnt lgkmcnt(0)" ::: "memory");   // done reading buf
    asm volatile("s_barrier" ::: "memory");              // safe to overwrite buf next iter
  }

  // epilogue 1: bias + sigmoid -> gbuf (f16, stride 128, octet-swizzled).
  // The K-loop's final barrier guarantees all staging reads are complete.
  #pragma unroll
  for (int i = 0; i < 4; ++i)
    #pragma unroll
    for (int j = 0; j < 4; ++j) {
      int col = wn + j * 16 + mrow;
      int oct = col >> 3, sub = col & 7;
      #pragma unroll
      for (int r = 0; r < 4; ++r) {
        int row = wm + i * 16 + kg * 4 + r;
        float z = acc[i][j][r] + bv[j];
        gbuf[row * 128 + ((oct ^ (row & 15)) << 3) + sub] =
            (_Float16)__builtin_amdgcn_rcpf(1.0f + __expf(-z));
      }
    }
  __syncthreads();

  // epilogue 2: one thread per (row, tree) — swizzled vector g-row load + register DFS.
  {
    const int row = tid >> 1, tr = tid & 1;
    const _Float16* grow = gbuf + row * 128;
    const int rx = row & 15;
    float g[63];
    #pragma unroll
    for (int c = 0; c < 8; ++c) {
      f16x8 gv = *(const f16x8*)(grow + (((tr * 8 + c) ^ rx) << 3));
      #pragma unroll
      for (int j = 0; j < 8; ++j) {
        int n = c * 8 + j;
        if (n < 63) g[n] = (float)gv[j];
      }
    }
    float P3[8];
    {
      float a0 = g[0],            a1 = 1.0f - g[0];
      float c0_ = a0 * g[1],      c1_ = a0 * (1.0f - g[1]);
      float c2_ = a1 * g[2],      c3_ = a1 * (1.0f - g[2]);
      P3[0] = c0_ * g[3];  P3[1] = c0_ * (1.0f - g[3]);
      P3[2] = c1_ * g[4];  P3[3] = c1_ * (1.0f - g[4]);
      P3[4] = c2_ * g[5];  P3[5] = c2_ * (1.0f - g[5]);
      P3[6] = c3_ * g[6];  P3[7] = c3_ * (1.0f - g[6]);
    }
    unsigned short* prow = P + (long)(b0 + row) * 4096 + (t0 + tr) * 64;
    #pragma unroll
    for (int o = 0; o < 8; ++o) {
      float g3 = g[7 + o];
      float q0 = P3[o] * g3, q1 = P3[o] * (1.0f - g3);
      float g4a = g[15 + 2 * o], g4b = g[16 + 2 * o];
      float r0 = q0 * g4a, r1 = q0 * (1.0f - g4a);
      float r2 = q1 * g4b, r3 = q1 * (1.0f - g4b);
      unsigned ou[4];
      #pragma unroll
      for (int h = 0; h < 4; ++h) {
        float g5 = g[31 + 4 * o + h];
        float rr2 = (h == 0) ? r0 : (h == 1) ? r1 : (h == 2) ? r2 : r3;
        ou[h] = pk_bf16(rr2 * g5, rr2 * (1.0f - g5));
      }
      *(uint4*)(prow + o * 8) = *(const uint4*)ou;
    }
  }
}

// ---------------- GEMM2: out += P(4096x4096) * Wv2^T (R6 measured-best) ----------
// 64-row tiles, split-K by 4 (chunks of 1024) -> grid (64,4) = 256 blocks,
// 32-iter dbuf pipeline, XOR bank swizzle, atomic f32 accumulate (8 MB total).
__global__ __launch_bounds__(256, 4) void gemm2_k(
    const unsigned short* __restrict__ P,    // [4096][4096] bf16
    const unsigned short* __restrict__ Wv2,  // [128][4096] bf16
    float* __restrict__ out)                 // [4096][128], pre-zeroed
{
  __shared__ unsigned short AsB[2][64 * 32];     // 8 KB
  __shared__ unsigned short BsB[2][128 * 32];    // 16 KB
  const int tid = threadIdx.x;
  const int wave = tid >> 6, lane = tid & 63;
  const int b0 = blockIdx.x * 64;
  const int k0 = blockIdx.y * 1024;              // K chunk of 1024

  const f32x4 zero = {0.f, 0.f, 0.f, 0.f};
  f32x4 acc[2][4];
  #pragma unroll
  for (int i = 0; i < 2; ++i)
    #pragma unroll
    for (int j = 0; j < 4; ++j) acc[i][j] = zero;

  const int g0 = wave * 64 + lane;           // A granules (256: 64 rows x 4 chunks)
  const int g1 = g0 + 256;                   // B granules (512 total)
  const int c0 = ((g0 & 3) ^ ((g0 >> 3) & 3)) * 8;
  const int c1 = ((g1 & 3) ^ ((g1 >> 3) & 3)) * 8;
  const unsigned short* Ag0 = P + (long)(b0 + (g0 >> 2)) * 4096 + k0 + c0;
  const unsigned short* Bg0 = Wv2 + (long)(g0 >> 2) * 4096 + k0 + c0;
  const unsigned short* Bg1 = Wv2 + (long)(g1 >> 2) * 4096 + k0 + c1;
  const int lofs = wave * 512;

  const int wm = (wave >> 1) * 32, wn = (wave & 1) * 64;
  const int mrow = lane & 15, kg = lane >> 4;
  const int slot = (kg ^ ((mrow >> 1) & 3)) * 8;

  gl_lds16(Ag0, AsB[0] + lofs);
  gl_lds16(Bg0, BsB[0] + lofs);
  gl_lds16(Bg1, BsB[0] + lofs + 2048);

  for (int it = 0; it < 32; ++it) {
    const int buf = it & 1;
    if (it < 31) {
      const int kk = (it + 1) * 32;
      const int nbuf = (it + 1) & 1;
      gl_lds16(Ag0 + kk, AsB[nbuf] + lofs);
      gl_lds16(Bg0 + kk, BsB[nbuf] + lofs);
      gl_lds16(Bg1 + kk, BsB[nbuf] + lofs + 2048);
      asm volatile("s_waitcnt vmcnt(3)" ::: "memory");
    } else {
      asm volatile("s_waitcnt vmcnt(0)" ::: "memory");
    }
    asm volatile("s_barrier" ::: "memory");

    bf16x8 fa[2], fb[4];
    #pragma unroll
    for (int i = 0; i < 2; ++i)
      fa[i] = *(const bf16x8*)(AsB[buf] + (wm + i * 16 + mrow) * 32 + slot);
    #pragma unroll
    for (int j = 0; j < 4; ++j)
      fb[j] = *(const bf16x8*)(BsB[buf] + (wn + j * 16 + mrow) * 32 + slot);
    #pragma unroll
    for (int i = 0; i < 2; ++i)
      #pragma unroll
      for (int j = 0; j < 4; ++j)
        acc[i][j] = __builtin_amdgcn_mfma_f32_16x16x32_bf16(fa[i], fb[j], acc[i][j], 0, 0, 0);

    asm volatile("s_waitcnt lgkmcnt(0)" ::: "memory");
    asm volatile("s_barrier" ::: "memory");
  }

  #pragma unroll
  for (int i = 0; i < 2; ++i)
    #pragma unroll
    for (int j = 0; j < 4; ++j) {
      int col = wn + j * 16 + mrow;
      #pragma unroll
      for (int r = 0; r < 4; ++r) {
        int row = wm + i * 16 + kg * 4 + r;
        atomicAdd(&out[(long)(b0 + row) * 128 + col], acc[i][j][r]);
      }
    }
}

extern "C" void kernel_launch(void* const* d_in, const int* in_sizes, int n_in,
                              void* d_out, int out_size, void* d_ws, size_t ws_size,
                              hipStream_t stream) {
  const float* x     = (const float*)d_in[0];
  const float* W     = (const float*)d_in[1];
  const float* b     = (const float*)d_in[2];
  const float* lw    = (const float*)d_in[3];
  const float* gates = (const float*)d_in[4];
  float* out = (float*)d_out;

  char* ws = (char*)d_ws;
  unsigned short* xb  = (unsigned short*)(ws);                    // 4 MB
  unsigned short* Wt  = (unsigned short*)(ws + (4l  << 20));      // 4 MB
  unsigned short* Wv2 = (unsigned short*)(ws + (8l  << 20));      // 1 MB
  unsigned short* P   = (unsigned short*)(ws + (16l << 20));      // 32 MB

  hipLaunchKernelGGL(prep_all_k,   dim3(2464),   dim3(256), 0, stream,
                     x, W, gates, lw, xb, Wt, Wv2, out);
  hipLaunchKernelGGL(gemm1_tree_k, dim3(32, 32), dim3(256), 0, stream, xb, Wt, b, P);
  hipLaunchKernelGGL(gemm2_k,      dim3(64, 4),  dim3(256), 0, stream, P, Wv2, out);
}

// Round 13
// 136.846 us; speedup vs baseline: 1.0009x; 1.0009x over previous
//
#include <hip/hip_runtime.h>
#include <stdint.h>

// Problem constants
#define BATCH 4096
#define DIN   512
#define NT    64      // trees
#define NL    64      // leaves
#define LD    128     // leaf dims

typedef __attribute__((ext_vector_type(8))) short bf16x8;
typedef __attribute__((ext_vector_type(8))) _Float16 f16x8;
typedef __attribute__((ext_vector_type(4))) float f32x4;

typedef const __attribute__((address_space(1))) unsigned char* gcp_t;
typedef __attribute__((address_space(3))) unsigned char* lp_t;

__device__ __forceinline__ void gl_lds16(const void* g, void* l) {
  __builtin_amdgcn_global_load_lds((gcp_t)g, (lp_t)l, 16, 0, 0);
}

// packed 2xf32 -> 2xbf16 (round-half-up) in 3 VALU: 2 adds + 1 v_perm
__device__ __forceinline__ unsigned pk_bf16(float a, float b) {
  union { float f; unsigned u; } ua, ub;
  ua.f = a; ub.f = b;
  return __builtin_amdgcn_perm(ub.u + 0x8000u, ua.u + 0x8000u, 0x07060302u);
}

// ---------------- merged prep kernel ----------------
// blocks [0,2048): x fp32 -> bf16
// blocks [2048,2304): W(63,512,64) -> Wt[t][n][d] bf16 (n padded to 64); 4 d-chunks per n
// blocks [2304,2432): w = lw * softmax(gates, t) -> Wv2[d][kappa] bf16, kappa = t*64+l
// blocks [2432,2464): zero d_out (folds the hipMemsetAsync launch into this kernel)
__global__ __launch_bounds__(256) void prep_all_k(
    const float* __restrict__ x, const float* __restrict__ W,
    const float* __restrict__ gates, const float* __restrict__ lw,
    unsigned short* __restrict__ xb, unsigned short* __restrict__ Wt,
    unsigned short* __restrict__ Wv2, float* __restrict__ out) {
  __shared__ float smem[12288];   // 48 KB
  const int bx = blockIdx.x;
  const int tid = threadIdx.x;

  if (bx < 2048) {
    // ---- prep x ----
    int i = bx * 256 + tid;
    float4 v = ((const float4*)x)[i];
    uint2 o;
    o.x = pk_bf16(v.x, v.y);
    o.y = pk_bf16(v.z, v.w);
    ((uint2*)xb)[i] = o;
  } else if (bx < 2304) {
    // ---- prep Wt ----
    int bb = bx - 2048;
    int n = bb >> 2, d0 = (bb & 3) * 128;
    float* buf = smem;   // [d_local][t], 128*64 floats = 32 KB
    if (n < 63) {
      for (int it = 0; it < 32; ++it) {
        int idx = it * 256 + tid;   // idx = d_local*64 + t
        buf[idx] = W[n * 32768 + (d0 + (idx >> 6)) * 64 + (idx & 63)];
      }
    }
    __syncthreads();
    int t = tid >> 2, q = tid & 3;
    unsigned vals[16];
    #pragma unroll
    for (int j = 0; j < 16; ++j) {
      float va = (n < 63) ? buf[(q * 32 + 2 * j) * 64 + t] : 0.0f;
      float vb = (n < 63) ? buf[(q * 32 + 2 * j + 1) * 64 + t] : 0.0f;
      vals[j] = (n < 63) ? pk_bf16(va, vb) : 0u;
    }
    uint4* dst = (uint4*)(Wt + t * 32768 + n * 512 + d0 + q * 32);
    const uint4* src = (const uint4*)vals;
    dst[0] = src[0]; dst[1] = src[1]; dst[2] = src[2]; dst[3] = src[3];
  } else if (bx < 2432) {
    // ---- prep Wv2 ----
    int d = bx - 2304;           // 0..127
    float* gb = smem;            // [l*64 + t]
    float* lb = smem + 4096;
    float* wv = smem + 8192;
    for (int it = 0; it < 16; ++it) {
      int idx = it * 256 + tid;  // l*64 + t
      int l = idx >> 6;
      int ga = l * 8192 + d * 64 + (idx & 63);
      gb[idx] = gates[ga];
      lb[idx] = lw[ga];
    }
    __syncthreads();
    int wave = tid >> 6, lane = tid & 63;
    for (int l = wave; l < 64; l += 4) {
      float v = gb[l * 64 + lane];
      float mx = v;
      for (int m = 32; m >= 1; m >>= 1) mx = fmaxf(mx, __shfl_xor(mx, m));
      float e = __expf(v - mx);
      float s = e;
      for (int m = 32; m >= 1; m >>= 1) s += __shfl_xor(s, m);
      wv[l * 64 + lane] = lb[l * 64 + lane] * e / s;
    }
    __syncthreads();
    #pragma unroll
    for (int c = 0; c < 2; ++c) {
      int k0 = tid * 16 + c * 8;
      unsigned o[4];
      #pragma unroll
      for (int j = 0; j < 4; ++j) {
        int ka = k0 + 2 * j, kb = k0 + 2 * j + 1;   // kappa = t*64 + l
        o[j] = pk_bf16(wv[(ka & 63) * 64 + (ka >> 6)], wv[(kb & 63) * 64 + (kb >> 6)]);
      }
      *(uint4*)(Wv2 + (long)d * 4096 + k0) = *(const uint4*)o;
    }
  } else {
    // ---- zero d_out: 2 MB = 131072 float4, 32 blocks x 256 threads x 16 ----
    float4 z = {0.f, 0.f, 0.f, 0.f};
    int base = (bx - 2432) * 256 + tid;
    float4* o4 = (float4*)out;
    #pragma unroll
    for (int k = 0; k < 16; ++k)
      o4[k * 8192 + base] = z;
  }
}

// ---------------- GEMM1 fused: logits -> sigmoid -> tree product -> P ----------------
// NEW TILE: 256 batch rows x 2 trees (128 node-cols), 512 threads (8 waves as 4x2
// subtiles of 64x64). Rationale: gemm1 is staging-BW bound from L2/LLC (per-CU
// staging 64 KB/iter vs ~56 B/cyc/CU L2 ceiling); 256x128 tiles cut total staged
// volume 256 MB -> 196 MB (-23%). grid 512 blocks = 2/CU (LDS 64 KB), 16 waves/CU
// unchanged, VGPR/wave unchanged (launch_bounds(512,4) -> cap 128, no spill).
// Double-buffered staging (48 KB) + gbuf 256x128 f16 (64 KB) overlay union.
// XOR bank swizzle on staging; octet XOR swizzle on gbuf (conflict-free, R10).
__global__ __launch_bounds__(512, 4) void gemm1_tree_k(
    const unsigned short* __restrict__ xb,   // [4096][512] bf16
    const unsigned short* __restrict__ Wt,   // [64][64][512] bf16
    const float* __restrict__ bias,          // [63][64]
    unsigned short* __restrict__ P)          // [4096][4096] bf16, col = t*64+l
{
  __shared__ __align__(16) char smem[65536];           // union{ As[2][16K]+Bs[2][8K] , gbuf 64K }
  unsigned short* AsB = (unsigned short*)smem;         // 2 x 8192 shorts
  unsigned short* BsB = (unsigned short*)(smem + 32768); // 2 x 4096 shorts
  _Float16* gbuf = (_Float16*)smem;                    // [256][128], octet-swizzled

  const int tid = threadIdx.x;
  const int wave = tid >> 6, lane = tid & 63;

  // XCD-aware remap: 512 blocks, per-XCD set = 4 b0 x 16 t0 -> A 1MB + B 2MB in L2
  const int lin = blockIdx.x;
  const int rr = lin & 7, kq = lin >> 3;               // kq in [0,64)
  const int b0 = ((kq & 3) | ((rr & 3) << 2)) * 256;   // 16 b0 tiles
  const int t0 = ((kq >> 2) | ((rr >> 2) << 4)) * 2;   // 32 t0 tiles

  const int wm = (wave >> 1) * 64, wn = (wave & 1) * 64;
  const int mrow = lane & 15, kg = lane >> 4;
  const int slot = (kg ^ ((mrow >> 1) & 3)) * 8;   // staging reader slot

  // bias in registers: lane needs bias[(j*16+mrow)*64 + t0 + tree] for j=0..3
  float bv[4];
  #pragma unroll
  for (int j = 0; j < 4; ++j) {
    int n = j * 16 + mrow;
    bv[j] = (n < 63) ? bias[n * 64 + t0 + (wave & 1)] : 0.0f;
  }

  const f32x4 zero = {0.f, 0.f, 0.f, 0.f};
  f32x4 acc[4][4];
  #pragma unroll
  for (int i = 0; i < 4; ++i)
    #pragma unroll
    for (int j = 0; j < 4; ++j) acc[i][j] = zero;

  // A granules: 1024 of 16 B (256 rows x 4 chunks); 512 lanes -> 2/lane.
  // B granules: 512 (128 n'-rows x 4 chunks) -> 1/lane.
  const int g0 = tid;            // A part 0
  const int g1 = tid + 512;      // A part 1
  const int c0 = ((g0 & 3) ^ ((g0 >> 3) & 3)) * 8;
  const int c1 = ((g1 & 3) ^ ((g1 >> 3) & 3)) * 8;
  const unsigned short* Ag0 = xb + (long)(b0 + (g0 >> 2)) * 512 + c0;
  const unsigned short* Ag1 = xb + (long)(b0 + (g1 >> 2)) * 512 + c1;
  const unsigned short* Bg0 = Wt + (long)(t0 * 64 + (g0 >> 2)) * 512 + c0;
  const int lofsA0 = wave * 512;          // wave-uniform LDS short-offsets
  const int lofsA1 = wave * 512 + 4096;
  const int lofsB  = wave * 512;

  // preload tile 0 into buffer 0
  gl_lds16(Ag0, AsB + lofsA0);
  gl_lds16(Ag1, AsB + lofsA1);
  gl_lds16(Bg0, BsB + lofsB);

  for (int it = 0; it < 16; ++it) {
    const int bufA = (it & 1) * 8192;
    const int bufB = (it & 1) * 4096;
    if (it < 15) {
      const int kk = (it + 1) * 32;
      const int nA = ((it + 1) & 1) * 8192;
      const int nB = ((it + 1) & 1) * 4096;
      gl_lds16(Ag0 + kk, AsB + nA + lofsA0);
      gl_lds16(Ag1 + kk, AsB + nA + lofsA1);
      gl_lds16(Bg0 + kk, BsB + nB + lofsB);
      asm volatile("s_waitcnt vmcnt(3)" ::: "memory");   // tile it's 3 loads done
    } else {
      asm volatile("s_waitcnt vmcnt(0)" ::: "memory");
    }
    asm volatile("s_barrier" ::: "memory");              // all waves staged tile it

    bf16x8 fa[4], fb[4];
    #pragma unroll
    for (int i = 0; i < 4; ++i)
      fa[i] = *(const bf16x8*)(AsB + bufA + (wm + i * 16 + mrow) * 32 + slot);
    #pragma unroll
    for (int j = 0; j < 4; ++j)
      fb[j] = *(const bf16x8*)(BsB + bufB + (wn + j * 16 + mrow) * 32 + slot);
    #pragma unroll
    for (int i = 0; i < 4; ++i)
      #pragma unroll
      for (int j = 0; j < 4; ++j)
        acc[i][j] = __builtin_amdgcn_mfma_f32_16x16x32_bf16(fa[i], fb[j], acc[i][j], 0, 0, 0);

    asm volatile("s_waitcnt lgkmcnt(0)" ::: "memory");   // done reading buf
    asm volatile("s_barrier" ::: "memory");              // safe to overwrite buf next iter
  }

  // epilogue 1: bias + sigmoid -> gbuf (f16, stride 128, octet-swizzled).
  // The K-loop's final barrier guarantees all staging reads are complete.
  #pragma unroll
  for (int i = 0; i < 4; ++i)
    #pragma unroll
    for (int j = 0; j < 4; ++j) {
      int col = wn + j * 16 + mrow;
      int oct = col >> 3, sub = col & 7;
      #pragma unroll
      for (int r = 0; r < 4; ++r) {
        int row = wm + i * 16 + kg * 4 + r;    // [0,256)
        float z = acc[i][j][r] + bv[j];
        gbuf[row * 128 + ((oct ^ (row & 15)) << 3) + sub] =
            (_Float16)__builtin_amdgcn_rcpf(1.0f + __expf(-z));
      }
    }
  __syncthreads();

  // epilogue 2: one thread per (row, tree): 512 threads = 256 rows x 2 trees.
  {
    const int row = tid >> 1, tr = tid & 1;
    const _Float16* grow = gbuf + row * 128;
    const int rx = row & 15;
    float g[63];
    #pragma unroll
    for (int c = 0; c < 8; ++c) {
      f16x8 gv = *(const f16x8*)(grow + (((tr * 8 + c) ^ rx) << 3));
      #pragma unroll
      for (int j = 0; j < 8; ++j) {
        int n = c * 8 + j;
        if (n < 63) g[n] = (float)gv[j];
      }
    }
    float P3[8];
    {
      float a0 = g[0],            a1 = 1.0f - g[0];
      float c0_ = a0 * g[1],      c1_ = a0 * (1.0f - g[1]);
      float c2_ = a1 * g[2],      c3_ = a1 * (1.0f - g[2]);
      P3[0] = c0_ * g[3];  P3[1] = c0_ * (1.0f - g[3]);
      P3[2] = c1_ * g[4];  P3[3] = c1_ * (1.0f - g[4]);
      P3[4] = c2_ * g[5];  P3[5] = c2_ * (1.0f - g[5]);
      P3[6] = c3_ * g[6];  P3[7] = c3_ * (1.0f - g[6]);
    }
    unsigned short* prow = P + (long)(b0 + row) * 4096 + (t0 + tr) * 64;
    #pragma unroll
    for (int o = 0; o < 8; ++o) {
      float g3 = g[7 + o];
      float q0 = P3[o] * g3, q1 = P3[o] * (1.0f - g3);
      float g4a = g[15 + 2 * o], g4b = g[16 + 2 * o];
      float r0 = q0 * g4a, r1 = q0 * (1.0f - g4a);
      float r2 = q1 * g4b, r3 = q1 * (1.0f - g4b);
      unsigned ou[4];
      #pragma unroll
      for (int h = 0; h < 4; ++h) {
        float g5 = g[31 + 4 * o + h];
        float rr2 = (h == 0) ? r0 : (h == 1) ? r1 : (h == 2) ? r2 : r3;
        ou[h] = pk_bf16(rr2 * g5, rr2 * (1.0f - g5));
      }
      *(uint4*)(prow + o * 8) = *(const uint4*)ou;
    }
  }
}

// ---------------- GEMM2: out += P(4096x4096) * Wv2^T (R6 measured-best) ----------
// 64-row tiles, split-K by 4 (chunks of 1024) -> grid (64,4) = 256 blocks,
// 32-iter dbuf pipeline, XOR bank swizzle, atomic f32 accumulate (8 MB total).
__global__ __launch_bounds__(256, 4) void gemm2_k(
    const unsigned short* __restrict__ P,    // [4096][4096] bf16
    const unsigned short* __restrict__ Wv2,  // [128][4096] bf16
    float* __restrict__ out)                 // [4096][128], pre-zeroed
{
  __shared__ unsigned short AsB[2][64 * 32];     // 8 KB
  __shared__ unsigned short BsB[2][128 * 32];    // 16 KB
  const int tid = threadIdx.x;
  const int wave = tid >> 6, lane = tid & 63;
  const int b0 = blockIdx.x * 64;
  const int k0 = blockIdx.y * 1024;              // K chunk of 1024

  const f32x4 zero = {0.f, 0.f, 0.f, 0.f};
  f32x4 acc[2][4];
  #pragma unroll
  for (int i = 0; i < 2; ++i)
    #pragma unroll
    for (int j = 0; j < 4; ++j) acc[i][j] = zero;

  const int g0 = wave * 64 + lane;           // A granules (256: 64 rows x 4 chunks)
  const int g1 = g0 + 256;                   // B granules (512 total)
  const int c0 = ((g0 & 3) ^ ((g0 >> 3) & 3)) * 8;
  const int c1 = ((g1 & 3) ^ ((g1 >> 3) & 3)) * 8;
  const unsigned short* Ag0 = P + (long)(b0 + (g0 >> 2)) * 4096 + k0 + c0;
  const unsigned short* Bg0 = Wv2 + (long)(g0 >> 2) * 4096 + k0 + c0;
  const unsigned short* Bg1 = Wv2 + (long)(g1 >> 2) * 4096 + k0 + c1;
  const int lofs = wave * 512;

  const int wm = (wave >> 1) * 32, wn = (wave & 1) * 64;
  const int mrow = lane & 15, kg = lane >> 4;
  const int slot = (kg ^ ((mrow >> 1) & 3)) * 8;

  gl_lds16(Ag0, AsB[0] + lofs);
  gl_lds16(Bg0, BsB[0] + lofs);
  gl_lds16(Bg1, BsB[0] + lofs + 2048);

  for (int it = 0; it < 32; ++it) {
    const int buf = it & 1;
    if (it < 31) {
      const int kk = (it + 1) * 32;
      const int nbuf = (it + 1) & 1;
      gl_lds16(Ag0 + kk, AsB[nbuf] + lofs);
      gl_lds16(Bg0 + kk, BsB[nbuf] + lofs);
      gl_lds16(Bg1 + kk, BsB[nbuf] + lofs + 2048);
      asm volatile("s_waitcnt vmcnt(3)" ::: "memory");
    } else {
      asm volatile("s_waitcnt vmcnt(0)" ::: "memory");
    }
    asm volatile("s_barrier" ::: "memory");

    bf16x8 fa[2], fb[4];
    #pragma unroll
    for (int i = 0; i < 2; ++i)
      fa[i] = *(const bf16x8*)(AsB[buf] + (wm + i * 16 + mrow) * 32 + slot);
    #pragma unroll
    for (int j = 0; j < 4; ++j)
      fb[j] = *(const bf16x8*)(BsB[buf] + (wn + j * 16 + mrow) * 32 + slot);
    #pragma unroll
    for (int i = 0; i < 2; ++i)
      #pragma unroll
      for (int j = 0; j < 4; ++j)
        acc[i][j] = __builtin_amdgcn_mfma_f32_16x16x32_bf16(fa[i], fb[j], acc[i][j], 0, 0, 0);

    asm volatile("s_waitcnt lgkmcnt(0)" ::: "memory");
    asm volatile("s_barrier" ::: "memory");
  }

  #pragma unroll
  for (int i = 0; i < 2; ++i)
    #pragma unroll
    for (int j = 0; j < 4; ++j) {
      int col = wn + j * 16 + mrow;
      #pragma unroll
      for (int r = 0; r < 4; ++r) {
        int row = wm + i * 16 + kg * 4 + r;
        atomicAdd(&out[(long)(b0 + row) * 128 + col], acc[i][j][r]);
      }
    }
}

extern "C" void kernel_launch(void* const* d_in, const int* in_sizes, int n_in,
                              void* d_out, int out_size, void* d_ws, size_t ws_size,
                              hipStream_t stream) {
  const float* x     = (const float*)d_in[0];
  const float* W     = (const float*)d_in[1];
  const float* b     = (const float*)d_in[2];
  const float* lw    = (const float*)d_in[3];
  const float* gates = (const float*)d_in[4];
  float* out = (float*)d_out;

  char* ws = (char*)d_ws;
  unsigned short* xb  = (unsigned short*)(ws);                    // 4 MB
  unsigned short* Wt  = (unsigned short*)(ws + (4l  << 20));      // 4 MB
  unsigned short* Wv2 = (unsigned short*)(ws + (8l  << 20));      // 1 MB
  unsigned short* P   = (unsigned short*)(ws + (16l << 20));      // 32 MB

  hipLaunchKernelGGL(prep_all_k,   dim3(2464), dim3(256), 0, stream,
                     x, W, gates, lw, xb, Wt, Wv2, out);
  hipLaunchKernelGGL(gemm1_tree_k, dim3(512),  dim3(512), 0, stream, xb, Wt, b, P);
  hipLaunchKernelGGL(gemm2_k,      dim3(64, 4), dim3(256), 0, stream, P, Wv2, out);
}

// Round 14
// 136.459 us; speedup vs baseline: 1.0038x; 1.0028x over previous
//
#include <hip/hip_runtime.h>
#include <stdint.h>

// Problem constants
#define BATCH 4096
#define DIN   512
#define NT    64      // trees
#define NL    64      // leaves
#define LD    128     // leaf dims

typedef __attribute__((ext_vector_type(8))) short bf16x8;
typedef __attribute__((ext_vector_type(8))) _Float16 f16x8;
typedef __attribute__((ext_vector_type(4))) float f32x4;

typedef const __attribute__((address_space(1))) unsigned char* gcp_t;
typedef __attribute__((address_space(3))) unsigned char* lp_t;

__device__ __forceinline__ void gl_lds16(const void* g, void* l) {
  __builtin_amdgcn_global_load_lds((gcp_t)g, (lp_t)l, 16, 0, 0);
}

// packed 2xf32 -> 2xbf16 (round-half-up) in 3 VALU: 2 adds + 1 v_perm
__device__ __forceinline__ unsigned pk_bf16(float a, float b) {
  union { float f; unsigned u; } ua, ub;
  ua.f = a; ub.f = b;
  return __builtin_amdgcn_perm(ub.u + 0x8000u, ua.u + 0x8000u, 0x07060302u);
}

// ---------------- merged prep kernel ----------------
// blocks [0,2048): x fp32 -> bf16
// blocks [2048,2304): W(63,512,64) -> Wt[t][n][d] bf16 (n padded to 64); 4 d-chunks per n
// blocks [2304,2432): w = lw * softmax(gates, t) -> Wv2[d][kappa] bf16, kappa = t*64+l
// blocks [2432,2464): zero d_out (folds the hipMemsetAsync launch into this kernel)
__global__ __launch_bounds__(256) void prep_all_k(
    const float* __restrict__ x, const float* __restrict__ W,
    const float* __restrict__ gates, const float* __restrict__ lw,
    unsigned short* __restrict__ xb, unsigned short* __restrict__ Wt,
    unsigned short* __restrict__ Wv2, float* __restrict__ out) {
  __shared__ float smem[12288];   // 48 KB
  const int bx = blockIdx.x;
  const int tid = threadIdx.x;

  if (bx < 2048) {
    // ---- prep x ----
    int i = bx * 256 + tid;
    float4 v = ((const float4*)x)[i];
    uint2 o;
    o.x = pk_bf16(v.x, v.y);
    o.y = pk_bf16(v.z, v.w);
    ((uint2*)xb)[i] = o;
  } else if (bx < 2304) {
    // ---- prep Wt ----
    int bb = bx - 2048;
    int n = bb >> 2, d0 = (bb & 3) * 128;
    float* buf = smem;   // [d_local][t], 128*64 floats = 32 KB
    if (n < 63) {
      for (int it = 0; it < 32; ++it) {
        int idx = it * 256 + tid;   // idx = d_local*64 + t
        buf[idx] = W[n * 32768 + (d0 + (idx >> 6)) * 64 + (idx & 63)];
      }
    }
    __syncthreads();
    int t = tid >> 2, q = tid & 3;
    unsigned vals[16];
    #pragma unroll
    for (int j = 0; j < 16; ++j) {
      float va = (n < 63) ? buf[(q * 32 + 2 * j) * 64 + t] : 0.0f;
      float vb = (n < 63) ? buf[(q * 32 + 2 * j + 1) * 64 + t] : 0.0f;
      vals[j] = (n < 63) ? pk_bf16(va, vb) : 0u;
    }
    uint4* dst = (uint4*)(Wt + t * 32768 + n * 512 + d0 + q * 32);
    const uint4* src = (const uint4*)vals;
    dst[0] = src[0]; dst[1] = src[1]; dst[2] = src[2]; dst[3] = src[3];
  } else if (bx < 2432) {
    // ---- prep Wv2 ----
    int d = bx - 2304;           // 0..127
    float* gb = smem;            // [l*64 + t]
    float* lb = smem + 4096;
    float* wv = smem + 8192;
    for (int it = 0; it < 16; ++it) {
      int idx = it * 256 + tid;  // l*64 + t
      int l = idx >> 6;
      int ga = l * 8192 + d * 64 + (idx & 63);
      gb[idx] = gates[ga];
      lb[idx] = lw[ga];
    }
    __syncthreads();
    int wave = tid >> 6, lane = tid & 63;
    for (int l = wave; l < 64; l += 4) {
      float v = gb[l * 64 + lane];
      float mx = v;
      for (int m = 32; m >= 1; m >>= 1) mx = fmaxf(mx, __shfl_xor(mx, m));
      float e = __expf(v - mx);
      float s = e;
      for (int m = 32; m >= 1; m >>= 1) s += __shfl_xor(s, m);
      wv[l * 64 + lane] = lb[l * 64 + lane] * e / s;
    }
    __syncthreads();
    #pragma unroll
    for (int c = 0; c < 2; ++c) {
      int k0 = tid * 16 + c * 8;
      unsigned o[4];
      #pragma unroll
      for (int j = 0; j < 4; ++j) {
        int ka = k0 + 2 * j, kb = k0 + 2 * j + 1;   // kappa = t*64 + l
        o[j] = pk_bf16(wv[(ka & 63) * 64 + (ka >> 6)], wv[(kb & 63) * 64 + (kb >> 6)]);
      }
      *(uint4*)(Wv2 + (long)d * 4096 + k0) = *(const uint4*)o;
    }
  } else {
    // ---- zero d_out: 2 MB = 131072 float4, 32 blocks x 256 threads x 16 ----
    float4 z = {0.f, 0.f, 0.f, 0.f};
    int base = (bx - 2432) * 256 + tid;
    float4* o4 = (float4*)out;
    #pragma unroll
    for (int k = 0; k < 16; ++k)
      o4[k * 8192 + base] = z;
  }
}

// ---------------- GEMM1 fused: logits -> sigmoid -> tree product -> P ----------------
// 256 batch rows x 2 trees (128 node-cols), 512 threads (8 waves, 4x2 subtiles of
// 64x64). TRI-BUFFERED staging, prefetch distance 2, ONE barrier per iter at
// UNCHANGED occupancy (LDS 72 KB vs 64 KB both -> 2 blocks/CU) — isolates
// barrier-count/prefetch-depth from R8's occupancy confound.
// Race-safe (R7-fix pattern): fused `vmcnt(N) lgkmcnt(0)` BEFORE the barrier drains
// the previous iter's ds_reads to registers; prefetch (which overwrites the buffer
// those reads used) is issued AFTER the barrier.
// XOR bank swizzle on staging; octet XOR swizzle on gbuf (conflict-free, R10);
// bias in VGPRs; launch_bounds(512,4) -> VGPR cap 128, no spill (R10 lesson).
__global__ __launch_bounds__(512, 4) void gemm1_tree_k(
    const unsigned short* __restrict__ xb,   // [4096][512] bf16
    const unsigned short* __restrict__ Wt,   // [64][64][512] bf16
    const float* __restrict__ bias,          // [63][64]
    unsigned short* __restrict__ P)          // [4096][4096] bf16, col = t*64+l
{
  __shared__ __align__(16) char smem[73728];             // union{ As[3][16K]+Bs[3][8K], gbuf 64K }
  unsigned short* AsB = (unsigned short*)smem;           // 3 x 8192 shorts
  unsigned short* BsB = (unsigned short*)(smem + 49152); // 3 x 4096 shorts
  _Float16* gbuf = (_Float16*)smem;                      // [256][128], octet-swizzled

  const int tid = threadIdx.x;
  const int wave = tid >> 6, lane = tid & 63;

  // XCD-aware remap: per-XCD set = 4 b0 x 16 t0 -> A 1MB + B 2MB in L2
  const int lin = blockIdx.x;
  const int rr = lin & 7, kq = lin >> 3;               // kq in [0,64)
  const int b0 = ((kq & 3) | ((rr & 3) << 2)) * 256;   // 16 b0 tiles
  const int t0 = ((kq >> 2) | ((rr >> 2) << 4)) * 2;   // 32 t0 tiles

  const int wm = (wave >> 1) * 64, wn = (wave & 1) * 64;
  const int mrow = lane & 15, kg = lane >> 4;
  const int slot = (kg ^ ((mrow >> 1) & 3)) * 8;   // staging reader slot

  // bias in registers
  float bv[4];
  #pragma unroll
  for (int j = 0; j < 4; ++j) {
    int n = j * 16 + mrow;
    bv[j] = (n < 63) ? bias[n * 64 + t0 + (wave & 1)] : 0.0f;
  }

  const f32x4 zero = {0.f, 0.f, 0.f, 0.f};
  f32x4 acc[4][4];
  #pragma unroll
  for (int i = 0; i < 4; ++i)
    #pragma unroll
    for (int j = 0; j < 4; ++j) acc[i][j] = zero;

  // A granules: 1024 of 16 B (256 rows x 4 chunks); 512 lanes -> 2/lane.
  // B granules: 512 (128 n'-rows x 4 chunks) -> 1/lane.
  const int g0 = tid;
  const int g1 = tid + 512;
  const int c0 = ((g0 & 3) ^ ((g0 >> 3) & 3)) * 8;
  const int c1 = ((g1 & 3) ^ ((g1 >> 3) & 3)) * 8;
  const unsigned short* Ag0 = xb + (long)(b0 + (g0 >> 2)) * 512 + c0;
  const unsigned short* Ag1 = xb + (long)(b0 + (g1 >> 2)) * 512 + c1;
  const unsigned short* Bg0 = Wt + (long)(t0 * 64 + (g0 >> 2)) * 512 + c0;
  const int lofsA0 = wave * 512;          // wave-uniform LDS short-offsets
  const int lofsA1 = wave * 512 + 4096;
  const int lofsB  = wave * 512;

  // preload tile 0 -> buf 0, tile 1 -> buf 1 (3 loads each)
  gl_lds16(Ag0, AsB + lofsA0);
  gl_lds16(Ag1, AsB + lofsA1);
  gl_lds16(Bg0, BsB + lofsB);
  gl_lds16(Ag0 + 32, AsB + 8192 + lofsA0);
  gl_lds16(Ag1 + 32, AsB + 8192 + lofsA1);
  gl_lds16(Bg0 + 32, BsB + 4096 + lofsB);

  for (int it = 0; it < 16; ++it) {
    const int bufA = (it % 3) * 8192;
    const int bufB = (it % 3) * 4096;
    // <=6 loads outstanding; oldest 3 are tile `it`: vmcnt(3) completes it.
    // lgkmcnt(0) drains prev iter's ds_reads BEFORE the barrier (race fix).
    if (it < 15) {
      asm volatile("s_waitcnt vmcnt(3) lgkmcnt(0)" ::: "memory");
    } else {
      asm volatile("s_waitcnt vmcnt(0) lgkmcnt(0)" ::: "memory");
    }
    asm volatile("s_barrier" ::: "memory");   // tile it staged; buf (it+2)%3's readers drained

    if (it < 14) {                            // prefetch tile it+2 (post-barrier: safe)
      const int kk = (it + 2) * 32;
      const int nA = ((it + 2) % 3) * 8192;
      const int nB = ((it + 2) % 3) * 4096;
      gl_lds16(Ag0 + kk, AsB + nA + lofsA0);
      gl_lds16(Ag1 + kk, AsB + nA + lofsA1);
      gl_lds16(Bg0 + kk, BsB + nB + lofsB);
    }

    bf16x8 fa[4], fb[4];
    #pragma unroll
    for (int i = 0; i < 4; ++i)
      fa[i] = *(const bf16x8*)(AsB + bufA + (wm + i * 16 + mrow) * 32 + slot);
    #pragma unroll
    for (int j = 0; j < 4; ++j)
      fb[j] = *(const bf16x8*)(BsB + bufB + (wn + j * 16 + mrow) * 32 + slot);
    #pragma unroll
    for (int i = 0; i < 4; ++i)
      #pragma unroll
      for (int j = 0; j < 4; ++j)
        acc[i][j] = __builtin_amdgcn_mfma_f32_16x16x32_bf16(fa[i], fb[j], acc[i][j], 0, 0, 0);
  }

  __syncthreads();   // full drain + barrier before gbuf overlays the staging buffers

  // epilogue 1: bias + sigmoid -> gbuf (f16, stride 128, octet-swizzled).
  #pragma unroll
  for (int i = 0; i < 4; ++i)
    #pragma unroll
    for (int j = 0; j < 4; ++j) {
      int col = wn + j * 16 + mrow;
      int oct = col >> 3, sub = col & 7;
      #pragma unroll
      for (int r = 0; r < 4; ++r) {
        int row = wm + i * 16 + kg * 4 + r;    // [0,256)
        float z = acc[i][j][r] + bv[j];
        gbuf[row * 128 + ((oct ^ (row & 15)) << 3) + sub] =
            (_Float16)__builtin_amdgcn_rcpf(1.0f + __expf(-z));
      }
    }
  __syncthreads();

  // epilogue 2: one thread per (row, tree): 512 threads = 256 rows x 2 trees.
  {
    const int row = tid >> 1, tr = tid & 1;
    const _Float16* grow = gbuf + row * 128;
    const int rx = row & 15;
    float g[63];
    #pragma unroll
    for (int c = 0; c < 8; ++c) {
      f16x8 gv = *(const f16x8*)(grow + (((tr * 8 + c) ^ rx) << 3));
      #pragma unroll
      for (int j = 0; j < 8; ++j) {
        int n = c * 8 + j;
        if (n < 63) g[n] = (float)gv[j];
      }
    }
    float P3[8];
    {
      float a0 = g[0],            a1 = 1.0f - g[0];
      float c0_ = a0 * g[1],      c1_ = a0 * (1.0f - g[1]);
      float c2_ = a1 * g[2],      c3_ = a1 * (1.0f - g[2]);
      P3[0] = c0_ * g[3];  P3[1] = c0_ * (1.0f - g[3]);
      P3[2] = c1_ * g[4];  P3[3] = c1_ * (1.0f - g[4]);
      P3[4] = c2_ * g[5];  P3[5] = c2_ * (1.0f - g[5]);
      P3[6] = c3_ * g[6];  P3[7] = c3_ * (1.0f - g[6]);
    }
    unsigned short* prow = P + (long)(b0 + row) * 4096 + (t0 + tr) * 64;
    #pragma unroll
    for (int o = 0; o < 8; ++o) {
      float g3 = g[7 + o];
      float q0 = P3[o] * g3, q1 = P3[o] * (1.0f - g3);
      float g4a = g[15 + 2 * o], g4b = g[16 + 2 * o];
      float r0 = q0 * g4a, r1 = q0 * (1.0f - g4a);
      float r2 = q1 * g4b, r3 = q1 * (1.0f - g4b);
      unsigned ou[4];
      #pragma unroll
      for (int h = 0; h < 4; ++h) {
        float g5 = g[31 + 4 * o + h];
        float rr2 = (h == 0) ? r0 : (h == 1) ? r1 : (h == 2) ? r2 : r3;
        ou[h] = pk_bf16(rr2 * g5, rr2 * (1.0f - g5));
      }
      *(uint4*)(prow + o * 8) = *(const uint4*)ou;
    }
  }
}

// ---------------- GEMM2: out += P(4096x4096) * Wv2^T (R6 measured-best) ----------
// 64-row tiles, split-K by 4 (chunks of 1024) -> grid (64,4) = 256 blocks,
// 32-iter dbuf pipeline, XOR bank swizzle, atomic f32 accumulate (8 MB total).
__global__ __launch_bounds__(256, 4) void gemm2_k(
    const unsigned short* __restrict__ P,    // [4096][4096] bf16
    const unsigned short* __restrict__ Wv2,  // [128][4096] bf16
    float* __restrict__ out)                 // [4096][128], pre-zeroed
{
  __shared__ unsigned short AsB[2][64 * 32];     // 8 KB
  __shared__ unsigned short BsB[2][128 * 32];    // 16 KB
  const int tid = threadIdx.x;
  const int wave = tid >> 6, lane = tid & 63;
  const int b0 = blockIdx.x * 64;
  const int k0 = blockIdx.y * 1024;              // K chunk of 1024

  const f32x4 zero = {0.f, 0.f, 0.f, 0.f};
  f32x4 acc[2][4];
  #pragma unroll
  for (int i = 0; i < 2; ++i)
    #pragma unroll
    for (int j = 0; j < 4; ++j) acc[i][j] = zero;

  const int g0 = wave * 64 + lane;           // A granules (256: 64 rows x 4 chunks)
  const int g1 = g0 + 256;                   // B granules (512 total)
  const int c0 = ((g0 & 3) ^ ((g0 >> 3) & 3)) * 8;
  const int c1 = ((g1 & 3) ^ ((g1 >> 3) & 3)) * 8;
  const unsigned short* Ag0 = P + (long)(b0 + (g0 >> 2)) * 4096 + k0 + c0;
  const unsigned short* Bg0 = Wv2 + (long)(g0 >> 2) * 4096 + k0 + c0;
  const unsigned short* Bg1 = Wv2 + (long)(g1 >> 2) * 4096 + k0 + c1;
  const int lofs = wave * 512;

  const int wm = (wave >> 1) * 32, wn = (wave & 1) * 64;
  const int mrow = lane & 15, kg = lane >> 4;
  const int slot = (kg ^ ((mrow >> 1) & 3)) * 8;

  gl_lds16(Ag0, AsB[0] + lofs);
  gl_lds16(Bg0, BsB[0] + lofs);
  gl_lds16(Bg1, BsB[0] + lofs + 2048);

  for (int it = 0; it < 32; ++it) {
    const int buf = it & 1;
    if (it < 31) {
      const int kk = (it + 1) * 32;
      const int nbuf = (it + 1) & 1;
      gl_lds16(Ag0 + kk, AsB[nbuf] + lofs);
      gl_lds16(Bg0 + kk, BsB[nbuf] + lofs);
      gl_lds16(Bg1 + kk, BsB[nbuf] + lofs + 2048);
      asm volatile("s_waitcnt vmcnt(3)" ::: "memory");
    } else {
      asm volatile("s_waitcnt vmcnt(0)" ::: "memory");
    }
    asm volatile("s_barrier" ::: "memory");

    bf16x8 fa[2], fb[4];
    #pragma unroll
    for (int i = 0; i < 2; ++i)
      fa[i] = *(const bf16x8*)(AsB[buf] + (wm + i * 16 + mrow) * 32 + slot);
    #pragma unroll
    for (int j = 0; j < 4; ++j)
      fb[j] = *(const bf16x8*)(BsB[buf] + (wn + j * 16 + mrow) * 32 + slot);
    #pragma unroll
    for (int i = 0; i < 2; ++i)
      #pragma unroll
      for (int j = 0; j < 4; ++j)
        acc[i][j] = __builtin_amdgcn_mfma_f32_16x16x32_bf16(fa[i], fb[j], acc[i][j], 0, 0, 0);

    asm volatile("s_waitcnt lgkmcnt(0)" ::: "memory");
    asm volatile("s_barrier" ::: "memory");
  }

  #pragma unroll
  for (int i = 0; i < 2; ++i)
    #pragma unroll
    for (int j = 0; j < 4; ++j) {
      int col = wn + j * 16 + mrow;
      #pragma unroll
      for (int r = 0; r < 4; ++r) {
        int row = wm + i * 16 + kg * 4 + r;
        atomicAdd(&out[(long)(b0 + row) * 128 + col], acc[i][j][r]);
      }
    }
}

extern "C" void kernel_launch(void* const* d_in, const int* in_sizes, int n_in,
                              void* d_out, int out_size, void* d_ws, size_t ws_size,
                              hipStream_t stream) {
  const float* x     = (const float*)d_in[0];
  const float* W     = (const float*)d_in[1];
  const float* b     = (const float*)d_in[2];
  const float* lw    = (const float*)d_in[3];
  const float* gates = (const float*)d_in[4];
  float* out = (float*)d_out;

  char* ws = (char*)d_ws;
  unsigned short* xb  = (unsigned short*)(ws);                    // 4 MB
  unsigned short* Wt  = (unsigned short*)(ws + (4l  << 20));      // 4 MB
  unsigned short* Wv2 = (unsigned short*)(ws + (8l  << 20));      // 1 MB
  unsigned short* P   = (unsigned short*)(ws + (16l << 20));      // 32 MB

  hipLaunchKernelGGL(prep_all_k,   dim3(2464), dim3(256), 0, stream,
                     x, W, gates, lw, xb, Wt, Wv2, out);
  hipLaunchKernelGGL(gemm1_tree_k, dim3(512),  dim3(512), 0, stream, xb, Wt, b, P);
  hipLaunchKernelGGL(gemm2_k,      dim3(64, 4), dim3(256), 0, stream, P, Wv2, out);
}